// Round 5
// baseline (2294.160 us; speedup 1.0000x reference)
//
#include <hip/hip_runtime.h>
#include <hip/hip_bf16.h>
#include <math.h>

constexpr int B_ = 4, N_ = 8192, H_ = 8;
constexpr float SQT    = 0.35355339059327373f;   // sqrt(SOFTMAX_TEMP) = sqrt(1/8)
constexpr float RFF_S  = 0.17677669529663687f;   // sqrt(2/64)
constexpr float RATIO  = 0.0625f;                // 256^-0.5
constexpr float SM_EPS = 1e-6f;
constexpr float NORM_EPS = 1e-6f;

// ws layout (float offsets)
constexpr int OFF_CONST = 0;       // 64: [h*8+0..2]=sqrt(new_qw), [h*8+3..4]=sqrt(alpha); [63]=mask flag
constexpr int OFF_FLAG  = 63;      // 0=int32, 1=uint8, 2=int64
constexpr int OFF_MK    = 64;      // 32
constexpr int OFF_NMASK = 96;      // 32
constexpr int OFF_KSUM  = 128;     // 32*256
constexpr int OFF_VSUM  = 8320;    // 32*64
constexpr int OFF_BMAX  = 10368;   // 512
constexpr int OFF_CTX   = 10880;   // 32*256*64
constexpr int OFF_PROJT = 535168;  // 48*256*4  (projT4[dq][f][4])
constexpr int OFF_OWT   = 584320;  // 512*64    (out_wT[c][j])
constexpr int ZERO_BEG  = OFF_NMASK;
constexpr int ZERO_END  = OFF_PROJT;

__global__ __launch_bounds__(256)
void k_consts(const float* __restrict__ wrpe, const float* __restrict__ proj,
              const float* __restrict__ outw, const unsigned int* __restrict__ maskw,
              float* __restrict__ W) {
  __shared__ float exs[128];
  __shared__ float qwv[8][2];
  __shared__ int f_gt1;
  __shared__ int f_oddnz;
  __shared__ int f_evennz;
  int tid = threadIdx.x;
  if (tid == 0) { f_gt1 = 0; f_oddnz = 0; f_evennz = 0; }
  __syncthreads();
  {
    int gt1 = 0, oddnz = 0, evennz = 0;
    for (int i = tid; i < 8192; i += 256) {
      unsigned int v = maskw[i];
      if (v > 1u) gt1 = 1;
      if (v != 0u) { if (i & 1) oddnz = 1; else evennz = 1; }
    }
    if (gt1)    atomicOr(&f_gt1, 1);
    if (oddnz)  atomicOr(&f_oddnz, 1);
    if (evennz) atomicOr(&f_evennz, 1);
  }
  if (tid < 128) {
    int h = tid >> 4, r = (tid >> 3) & 1, c = (tid >> 2) & 1, k = tid & 3;
    float s = 0.f;
    for (int d = 0; d < 64; ++d) s += wrpe[(h*64 + d)*16 + r*8 + c*4 + k];
    exs[tid] = expf(fminf(s, 50.f));
  }
  __syncthreads();
  if (tid == 0) {
    float flag = 0.f;
    if (f_gt1) flag = 1.f;
    else if (!f_oddnz && f_evennz) flag = 2.f;
    W[OFF_FLAG] = flag;
  }
  if (tid < 32) {
    int h = tid >> 2, r = (tid >> 1) & 1, c = tid & 1;
    float s = 0.f;
    for (int k = 0; k < 4; ++k) s += exs[h*16 + r*8 + c*4 + k];
    if (c == 0) W[OFF_CONST + h*8 + 3 + r] = sqrtf(s);   // sqrt(alpha[h][r])
    else        qwv[h][r] = s;
  }
  __syncthreads();
  if (tid < 8) {
    int h = tid;
    float s0 = sqrtf(qwv[h][0]), s1 = sqrtf(qwv[h][1]);
    W[OFF_CONST + h*8 + 0] = s0;   // new_qw = [qw0, qw0, qw1]
    W[OFF_CONST + h*8 + 1] = s0;
    W[OFF_CONST + h*8 + 2] = s1;
  }
  for (int i = tid; i < 512; i += 256) W[OFF_BMAX + i] = -INFINITY;
  // projT4[(dq*256+f)*4 + j] = proj[f*192 + dq*4 + j]
  for (int i = tid; i < 48*256; i += 256) {
    int dq = i >> 8, f = i & 255;
    float4 v = *(const float4*)&proj[f*192 + dq*4];
    *(float4*)&W[OFF_PROJT + i*4] = v;
  }
  // out_wT[c][j] = out_w[j][c]
  for (int i = tid; i < 512*64; i += 256) {
    int c = i >> 6, j = i & 63;
    W[OFF_OWT + c*64 + j] = outw[j*512 + c];
  }
}

__device__ __forceinline__ int read_mask(const void* maskp, int mtype, size_t idx) {
  if (mtype == 1) return (int)((const unsigned char*)maskp)[idx];
  if (mtype == 2) return (int)((const long long*)maskp)[idx];
  return ((const int*)maskp)[idx];
}

__global__ __launch_bounds__(256)
void k_pass1(const float* __restrict__ key, const float* __restrict__ value,
             const float* __restrict__ coords, const void* __restrict__ maskp,
             const float* __restrict__ omR_g, const float* __restrict__ omA_g,
             float* __restrict__ W) {
  constexpr int NCH = 16, CHUNK = 512;
  int bh = blockIdx.x / NCH, ch = blockIdx.x % NCH;
  int b = bh >> 3, h = bh & 7;
  int tid = threadIdx.x;
  __shared__ __align__(16) float kc[16][192];
  __shared__ __align__(16) float vt[16][64];
  __shared__ float sxyz[16][3];
  __shared__ float mtile[16];
  __shared__ float diag[16];
  __shared__ float red[16][16];
  __shared__ float omR[64], omA[32];
  __shared__ float mred[256];

  if (tid < 64) omR[tid] = omR_g[tid];
  if (tid < 32) omA[tid] = omA_g[tid];
  int mtype = (int)W[OFF_FLAG];
  float s0 = W[OFF_CONST + h*8 + 0];
  float s1 = W[OFF_CONST + h*8 + 1];
  float s2 = W[OFF_CONST + h*8 + 2];
  float a0 = W[OFF_CONST + h*8 + 3] * RFF_S;
  float a1 = W[OFF_CONST + h*8 + 4] * RFF_S;

  float ctx[64];
  #pragma unroll
  for (int e = 0; e < 64; ++e) ctx[e] = 0.f;
  float ksum_acc = 0.f, maxd = -INFINITY;
  float vs = 0.f, nm = 0.f;

  int r = tid >> 4, l = tid & 15;
  for (int t = 0; t < CHUNK/16; ++t) {
    int n = ch*CHUNK + t*16 + r;
    __syncthreads();
    {
      const float* kp = key + ((size_t)b*N_ + n)*512 + h*64 + l*4;
      float4 kv = *(const float4*)kp;
      kc[r][l*4+0] = kv.x*SQT; kc[r][l*4+1] = kv.y*SQT;
      kc[r][l*4+2] = kv.z*SQT; kc[r][l*4+3] = kv.w*SQT;
      const float* vp = value + ((size_t)b*N_ + n)*512 + h*64 + l*4;
      *(float4*)&vt[r][l*4] = *(const float4*)vp;
      if (l == 0) {
        const float* cp = coords + ((size_t)b*N_ + n)*3;
        sxyz[r][0] = cp[0]*s0; sxyz[r][1] = cp[1]*s1; sxyz[r][2] = cp[2]*s2;
        mtile[r] = (read_mask(maskp, mtype, (size_t)b*N_ + n) != 0) ? 1.f : 0.f;
      }
    }
    __syncthreads();
    {
      float px = sxyz[r][0], py = sxyz[r][1], pz = sxyz[r][2];
      #pragma unroll
      for (int i = 0; i < 4; ++i) {
        int idx = l + 16*i;
        if (idx < 32) {
          float u = px*omR[idx] + py*omR[32+idx];
          float sn, cs; sincosf(u, &sn, &cs);
          kc[r][64+idx] = cs*a0; kc[r][96+idx] = sn*a0;
        } else {
          int j = idx - 32;
          float u = pz*omA[j];
          float sn, cs; sincosf(u, &sn, &cs);
          kc[r][128+j] = cs*a1; kc[r][160+j] = sn*a1;
        }
      }
    }
    __syncthreads();
    {
      float s = 0.f;
      #pragma unroll
      for (int i = 0; i < 12; ++i) { float v = kc[r][l*12+i]; s += v*v; }
      red[r][l] = s;
    }
    __syncthreads();
    if (l == 0) {
      float s = 0.f;
      #pragma unroll
      for (int i = 0; i < 16; ++i) s += red[r][i];
      diag[r] = 0.5f*s;
    }
    __syncthreads();
    float dash[16];
    #pragma unroll
    for (int rr = 0; rr < 16; ++rr) dash[rr] = 0.f;
    const float4* pT = (const float4*)&W[OFF_PROJT];
    for (int dq = 0; dq < 48; ++dq) {
      float4 p = pT[dq*256 + tid];
      #pragma unroll
      for (int rr = 0; rr < 16; ++rr) {
        float4 c = *(const float4*)&kc[rr][dq*4];
        dash[rr] = fmaf(p.x, c.x, fmaf(p.y, c.y, fmaf(p.z, c.z, fmaf(p.w, c.w, dash[rr]))));
      }
    }
    #pragma unroll 1
    for (int rr = 0; rr < 16; ++rr) {
      float dv = dash[rr];
      maxd = fmaxf(maxd, dv);
      if (mtile[rr] != 0.f) {
        float E = expf(dv - diag[rr]);
        ksum_acc += E;
        const float4* v4p = (const float4*)&vt[rr][0];
        #pragma unroll
        for (int e4 = 0; e4 < 16; ++e4) {
          float4 v4 = v4p[e4];
          ctx[e4*4+0] = fmaf(E, v4.x, ctx[e4*4+0]);
          ctx[e4*4+1] = fmaf(E, v4.y, ctx[e4*4+1]);
          ctx[e4*4+2] = fmaf(E, v4.z, ctx[e4*4+2]);
          ctx[e4*4+3] = fmaf(E, v4.w, ctx[e4*4+3]);
        }
      }
    }
    if (tid < 64) {
      #pragma unroll 1
      for (int rr = 0; rr < 16; ++rr)
        if (mtile[rr] != 0.f) vs += vt[rr][tid];
    }
    if (tid == 0) {
      for (int rr = 0; rr < 16; ++rr) nm += mtile[rr];
    }
  }
  atomicAdd(&W[OFF_KSUM + bh*256 + tid], ksum_acc);
  float* ctxg = &W[OFF_CTX + ((size_t)bh*256 + tid)*64];
  for (int e = 0; e < 64; ++e) atomicAdd(&ctxg[e], ctx[e]);
  if (tid < 64) atomicAdd(&W[OFF_VSUM + bh*64 + tid], vs);
  if (tid == 0) atomicAdd(&W[OFF_NMASK + bh], nm);
  mred[tid] = maxd;
  __syncthreads();
  for (int s = 128; s > 0; s >>= 1) {
    if (tid < s) mred[tid] = fmaxf(mred[tid], mred[tid+s]);
    __syncthreads();
  }
  if (tid == 0) W[OFF_BMAX + blockIdx.x] = mred[0];
}

__global__ void k_mkred(float* __restrict__ W) {
  int i = threadIdx.x;
  if (i < 32) {
    float m = -INFINITY;
    for (int c = 0; c < 16; ++c) m = fmaxf(m, W[OFF_BMAX + i*16 + c]);
    W[OFF_MK + i] = m;
  }
}

__global__ __launch_bounds__(256)
void k_finalize(float* __restrict__ W) {
  int bh = blockIdx.x;
  int tid = threadIdx.x;
  float emk  = RATIO * expf(-W[OFF_MK + bh]);
  float epsr = RATIO * SM_EPS;
  float nm = W[OFF_NMASK + bh];
  {
    float* ks = &W[OFF_KSUM + bh*256];
    ks[tid] = emk*ks[tid] + epsr*nm;
  }
  float* ctx = &W[OFF_CTX + (size_t)bh*16384];
  const float* vsum = &W[OFF_VSUM + bh*64];
  for (int i = tid; i < 16384; i += 256) {
    int e = i & 63;
    ctx[i] = emk*ctx[i] + epsr*vsum[e];
  }
}

__global__ __launch_bounds__(256)
void k_pass2(const float* __restrict__ query, const float* __restrict__ coords,
             const float* __restrict__ omR_g, const float* __restrict__ omA_g,
             const float* __restrict__ outb, const float* __restrict__ W,
             float* __restrict__ out) {
  int b  = blockIdx.x >> 9;          // N/16 = 512 tiles per batch
  int n0 = (blockIdx.x & 511) * 16;
  int tid = threadIdx.x;
  __shared__ __align__(16) float kc[16][192];
  __shared__ __align__(16) float qp[16][256];
  __shared__ __align__(16) float attn[16][64];
  __shared__ float ksl[256];
  __shared__ float sxyz[16][3];
  __shared__ float diag[16];
  __shared__ float mq[16];
  __shared__ float dnm[16];
  __shared__ float red[16][16];
  __shared__ float omR[64], omA[32];

  if (tid < 64) omR[tid] = omR_g[tid];
  if (tid < 32) omA[tid] = omA_g[tid];

  int r = tid >> 4, l = tid & 15;
  int rg = tid >> 6, e = tid & 63;
  float facc[4] = {0.f, 0.f, 0.f, 0.f};

  for (int h = 0; h < 8; ++h) {
    int bh = b*8 + h;
    float s0 = W[OFF_CONST + h*8 + 0];
    float s1 = W[OFF_CONST + h*8 + 1];
    float s2 = W[OFF_CONST + h*8 + 2];
    float a0 = W[OFF_CONST + h*8 + 3] * RFF_S;
    float a1 = W[OFF_CONST + h*8 + 4] * RFF_S;
    __syncthreads();
    ksl[tid] = W[OFF_KSUM + bh*256 + tid];
    {
      int n = n0 + r;
      const float* qpr = query + ((size_t)b*N_ + n)*512 + h*64 + l*4;
      float4 qv = *(const float4*)qpr;
      kc[r][l*4+0] = qv.x*SQT; kc[r][l*4+1] = qv.y*SQT;
      kc[r][l*4+2] = qv.z*SQT; kc[r][l*4+3] = qv.w*SQT;
      if (l == 0) {
        const float* cp = coords + ((size_t)b*N_ + n)*3;
        sxyz[r][0] = cp[0]*s0; sxyz[r][1] = cp[1]*s1; sxyz[r][2] = cp[2]*s2;
      }
    }
    __syncthreads();
    {
      float px = sxyz[r][0], py = sxyz[r][1], pz = sxyz[r][2];
      #pragma unroll
      for (int i = 0; i < 4; ++i) {
        int idx = l + 16*i;
        if (idx < 32) {
          float u = px*omR[idx] + py*omR[32+idx];
          float sn, cs; sincosf(u, &sn, &cs);
          kc[r][64+idx] = cs*a0; kc[r][96+idx] = sn*a0;
        } else {
          int j = idx - 32;
          float u = pz*omA[j];
          float sn, cs; sincosf(u, &sn, &cs);
          kc[r][128+j] = cs*a1; kc[r][160+j] = sn*a1;
        }
      }
    }
    __syncthreads();
    {
      float s = 0.f;
      #pragma unroll
      for (int i = 0; i < 12; ++i) { float v = kc[r][l*12+i]; s += v*v; }
      red[r][l] = s;
    }
    __syncthreads();
    if (l == 0) {
      float s = 0.f;
      #pragma unroll
      for (int i = 0; i < 16; ++i) s += red[r][i];
      diag[r] = 0.5f*s;
    }
    __syncthreads();
    float dash[16];
    #pragma unroll
    for (int rr = 0; rr < 16; ++rr) dash[rr] = 0.f;
    const float4* pT = (const float4*)&W[OFF_PROJT];
    for (int dq = 0; dq < 48; ++dq) {
      float4 p = pT[dq*256 + tid];
      #pragma unroll
      for (int rr = 0; rr < 16; ++rr) {
        float4 c = *(const float4*)&kc[rr][dq*4];
        dash[rr] = fmaf(p.x, c.x, fmaf(p.y, c.y, fmaf(p.z, c.z, fmaf(p.w, c.w, dash[rr]))));
      }
    }
    #pragma unroll
    for (int rr = 0; rr < 16; ++rr) qp[rr][tid] = dash[rr];
    __syncthreads();
    {
      float m = -INFINITY;
      for (int fi = l; fi < 256; fi += 16) m = fmaxf(m, qp[r][fi]);
      red[r][l] = m;
    }
    __syncthreads();
    if (l == 0) {
      float m = -INFINITY;
      #pragma unroll
      for (int i = 0; i < 16; ++i) m = fmaxf(m, red[r][i]);
      mq[r] = m;
    }
    __syncthreads();
    #pragma unroll
    for (int rr = 0; rr < 16; ++rr) {
      float qv = RATIO * (expf(qp[rr][tid] - diag[rr] - mq[rr]) + SM_EPS);
      qp[rr][tid] = qv;
    }
    __syncthreads();
    {
      float s = 0.f;
      for (int fi = l; fi < 256; fi += 16) s += qp[r][fi] * ksl[fi];
      red[r][l] = s;
    }
    __syncthreads();
    if (l == 0) {
      float s = 0.f;
      #pragma unroll
      for (int i = 0; i < 16; ++i) s += red[r][i];
      dnm[r] = 1.f / (s + NORM_EPS);
    }
    __syncthreads();
    {
      const float* ctxg = &W[OFF_CTX + (size_t)bh*16384];
      float acc[4] = {0.f, 0.f, 0.f, 0.f};
      for (int fi = 0; fi < 256; ++fi) {
        float cx = ctxg[fi*64 + e];
        #pragma unroll
        for (int i = 0; i < 4; ++i) acc[i] = fmaf(qp[rg*4+i][fi], cx, acc[i]);
      }
      #pragma unroll
      for (int i = 0; i < 4; ++i) attn[rg*4+i][e] = acc[i] * dnm[rg*4+i];
    }
    __syncthreads();
    {
      const float* owT = &W[OFF_OWT + h*64*64];
      #pragma unroll 1
      for (int ee = 0; ee < 64; ++ee) {
        float wv = owT[ee*64 + e];   // j = e lane
        #pragma unroll
        for (int i = 0; i < 4; ++i) facc[i] = fmaf(attn[rg*4+i][ee], wv, facc[i]);
      }
    }
  }
  {
    float bj = outb[e];
    #pragma unroll
    for (int i = 0; i < 4; ++i) {
      int n = n0 + rg*4 + i;
      out[((size_t)b*N_ + n)*64 + e] = facc[i] + bj;   // f32 output!
    }
  }
}

extern "C" void kernel_launch(void* const* d_in, const int* in_sizes, int n_in,
                              void* d_out, int out_size, void* d_ws, size_t ws_size,
                              hipStream_t stream) {
  const float* query  = (const float*)d_in[0];
  const float* key    = (const float*)d_in[1];
  const float* value  = (const float*)d_in[2];
  const float* coords = (const float*)d_in[3];
  const void*  mask   = d_in[4];
  const float* wrpe   = (const float*)d_in[5];
  const float* omR    = (const float*)d_in[6];
  const float* omA    = (const float*)d_in[7];
  const float* proj   = (const float*)d_in[8];
  const float* outw   = (const float*)d_in[9];
  const float* outb   = (const float*)d_in[10];
  float* W = (float*)d_ws;
  float* out = (float*)d_out;

  hipMemsetAsync(W + ZERO_BEG, 0, (size_t)(ZERO_END - ZERO_BEG)*sizeof(float), stream);
  hipLaunchKernelGGL(k_consts,   dim3(1),    dim3(256), 0, stream, wrpe, proj, outw,
                     (const unsigned int*)mask, W);
  hipLaunchKernelGGL(k_pass1,    dim3(512),  dim3(256), 0, stream, key, value, coords, mask, omR, omA, W);
  hipLaunchKernelGGL(k_mkred,    dim3(1),    dim3(64),  0, stream, W);
  hipLaunchKernelGGL(k_finalize, dim3(32),   dim3(256), 0, stream, W);
  hipLaunchKernelGGL(k_pass2,    dim3(2048), dim3(256), 0, stream, query, coords, omR, omA, outb, W, out);
}